// Round 9
// baseline (330.074 us; speedup 1.0000x reference)
//
#include <hip/hip_runtime.h>
#include <hip/hip_bf16.h>
#include <stdint.h>

// Transformer-XL relative MHA on MI355X (gfx950), bf16 MFMA pipeline.
// B=2, Q=1024, M=1024, D=1024, H=16, DH=64, K=2048.
// Buffers are fp32 (reference dtypes); checker threshold 1.38e-3.
// Evidence log:
//  - async global_load_lds GEMM staging verified (R5==R6 identity, R7/R8 pass).
//  - R5 failure isolated to bpermute block-selection (banned); no-online-max
//    verified correct in R8 -> enables linear K-split partials this round.

typedef __bf16 bf16;
typedef __bf16 bf16x2 __attribute__((ext_vector_type(2)));
typedef __bf16 bf16x4 __attribute__((ext_vector_type(4)));
typedef __bf16 bf16x8 __attribute__((ext_vector_type(8)));
typedef float  f32x4  __attribute__((ext_vector_type(4)));

// ---------------------------------------------------------------- async copy
__device__ __forceinline__ void async_copy16(void* lds, const void* g) {
    auto gp = (const __attribute__((address_space(1))) void*)(uintptr_t)g;
    auto lp = (__attribute__((address_space(3))) void*)(uint32_t)(uintptr_t)lds;
    __builtin_amdgcn_global_load_lds(gp, lp, 16, 0, 0);
}

// ------------------------------------------------------- 128x128 GEMM core
// C[128,128] = A[m0:+128, :Kd] * Bt[n0:+128, :Kd]^T   (both bf16, K contiguous)
// acc[rb][cb] C-layout: row = m0 + wr + rb*16 + (lane>>4)*4 + reg,
//                       col = n0 + wc + cb*16 + (lane&15)
__device__ __forceinline__ void gemm128_core(
    const bf16* __restrict__ A, const bf16* __restrict__ Bt, const int Kd,
    const int m0, const int n0, bf16* As, bf16* Bs, f32x4 acc[4][4])
{
    const int tid  = threadIdx.x;
    const int lane = tid & 63;
    const int wave = tid >> 6;
    const int wr   = (wave >> 1) * 64;
    const int wc   = (wave & 1) * 64;
    const int lr   = lane & 15;
    const int q4   = lane >> 4;

#pragma unroll
    for (int i = 0; i < 4; ++i)
#pragma unroll
        for (int j = 0; j < 4; ++j) {
            acc[i][j][0] = 0.f; acc[i][j][1] = 0.f; acc[i][j][2] = 0.f; acc[i][j][3] = 0.f;
        }

    for (int k0 = 0; k0 < Kd; k0 += 32) {
#pragma unroll
        for (int it = 0; it < 2; ++it) {
            const int cb0   = (it * 4 + wave) * 64;   // wave-uniform chunk base
            const int chunk = cb0 + lane;
            const int row   = chunk >> 2;
            const int cg    = (chunk & 3) * 8;
            async_copy16(As + cb0 * 8, A  + (size_t)(m0 + row) * Kd + k0 + cg);
            async_copy16(Bs + cb0 * 8, Bt + (size_t)(n0 + row) * Kd + k0 + cg);
        }
        __syncthreads();
        bf16x8 af[4], bfr[4];
#pragma unroll
        for (int rb = 0; rb < 4; ++rb)
            af[rb] = *(const bf16x8*)&As[(wr + rb * 16 + lr) * 32 + q4 * 8];
#pragma unroll
        for (int cb = 0; cb < 4; ++cb)
            bfr[cb] = *(const bf16x8*)&Bs[(wc + cb * 16 + lr) * 32 + q4 * 8];
#pragma unroll
        for (int rb = 0; rb < 4; ++rb)
#pragma unroll
            for (int cb = 0; cb < 4; ++cb)
                acc[rb][cb] = __builtin_amdgcn_mfma_f32_16x16x32_bf16(af[rb], bfr[cb], acc[rb][cb], 0, 0, 0);
        __syncthreads();
    }
}

// ------------------------------------------------------------- prep kernels
__global__ __launch_bounds__(256) void k_tcast(const float* __restrict__ in,
                                               bf16* __restrict__ out, int R, int C)
{
    __shared__ float t[32][33];
    const int c0 = blockIdx.x * 32, r0 = blockIdx.y * 32;
    const int lc = threadIdx.x & 31, lrow = threadIdx.x >> 5;
#pragma unroll
    for (int p = 0; p < 4; ++p)
        t[lrow + p * 8][lc] = in[(size_t)(r0 + lrow + p * 8) * C + c0 + lc];
    __syncthreads();
#pragma unroll
    for (int p = 0; p < 4; ++p)
        out[(size_t)(c0 + lrow + p * 8) * R + r0 + lc] = (bf16)t[lc][lrow + p * 8];
}

__global__ __launch_bounds__(256) void k_cast_cat(const float* __restrict__ mem,
                                                  const float* __restrict__ inp,
                                                  bf16* __restrict__ catb)
{
    const int e   = (blockIdx.x * 256 + threadIdx.x) * 4;
    const int row = e >> 10, dc = e & 1023;
    const int b   = row >> 11, k = row & 2047;
    const float* src = (k < 1024) ? mem + ((size_t)b * 1024 + k) * 1024 + dc
                                  : inp + ((size_t)b * 1024 + (k - 1024)) * 1024 + dc;
    float4 f = *(const float4*)src;
    bf16x4 o; o[0] = (bf16)f.x; o[1] = (bf16)f.y; o[2] = (bf16)f.z; o[3] = (bf16)f.w;
    *(bf16x4*)&catb[e] = o;
}

__global__ __launch_bounds__(256) void k_cast(const float* __restrict__ in,
                                              bf16* __restrict__ out)
{
    const int e = (blockIdx.x * 256 + threadIdx.x) * 4;
    float4 f = *(const float4*)(in + e);
    bf16x4 o; o[0] = (bf16)f.x; o[1] = (bf16)f.y; o[2] = (bf16)f.z; o[3] = (bf16)f.w;
    *(bf16x4*)&out[e] = o;
}

// ---------------------------------------------------------------- QKV GEMM
__global__ __launch_bounds__(256) void k_gemm_qkv(
    const bf16* __restrict__ catb, const bf16* __restrict__ Wt,
    const float* __restrict__ bias, const float* __restrict__ u, const float* __restrict__ v,
    bf16* __restrict__ hq_u, bf16* __restrict__ hq_v,
    bf16* __restrict__ hk, bf16* __restrict__ hv)
{
    __shared__ bf16 lds[2 * 128 * 32];
    f32x4 acc[4][4];
    const int m0 = blockIdx.x * 128, n0 = blockIdx.y * 128;
    gemm128_core(catb, Wt, 1024, m0, n0, lds, lds + 128 * 32, acc);

    const int lane = threadIdx.x & 63, wave = threadIdx.x >> 6;
    const int wr = (wave >> 1) * 64, wc = (wave & 1) * 64;
    const int lr = lane & 15, q4 = lane >> 4;
#pragma unroll
    for (int rb = 0; rb < 4; ++rb) {
#pragma unroll
        for (int cb = 0; cb < 4; ++cb) {
            const int col  = n0 + wc + cb * 16 + lr;
            const int part = col >> 10;
            const int hd   = col & 1023;
            const int h    = hd >> 6, d = hd & 63;
            const float bcol = bias[col];
#pragma unroll
            for (int r = 0; r < 4; ++r) {
                const int row = m0 + wr + rb * 16 + q4 * 4 + r;
                const int b   = row >> 11, k = row & 2047;
                const float val = acc[rb][cb][r] + bcol;
                if (part == 0) {
                    if (k >= 1024) {
                        const size_t o = (((size_t)(b * 16 + h)) * 1024 + (k - 1024)) * 64 + d;
                        hq_u[o] = (bf16)(val + u[hd]);
                        hq_v[o] = (bf16)(val + v[hd]);
                    }
                } else if (part == 1) {
                    hv[(((size_t)(b * 16 + h)) * 2048 + k) * 64 + d] = (bf16)val;
                } else {
                    hk[(((size_t)(b * 16 + h)) * 2048 + k) * 64 + d] = (bf16)val;
                }
            }
        }
    }
}

// ------------------------------------------------------------------ R GEMM
__global__ __launch_bounds__(256) void k_gemm_r(
    const bf16* __restrict__ rb_, const bf16* __restrict__ Wt,
    const float* __restrict__ bias, bf16* __restrict__ hr)
{
    __shared__ bf16 lds[2 * 128 * 32];
    f32x4 acc[4][4];
    const int m0 = blockIdx.x * 128, n0 = blockIdx.y * 128;
    gemm128_core(rb_, Wt, 1024, m0, n0, lds, lds + 128 * 32, acc);

    const int lane = threadIdx.x & 63, wave = threadIdx.x >> 6;
    const int wr = (wave >> 1) * 64, wc = (wave & 1) * 64;
    const int lr = lane & 15, q4 = lane >> 4;
#pragma unroll
    for (int rb = 0; rb < 4; ++rb) {
#pragma unroll
        for (int cb = 0; cb < 4; ++cb) {
            const int col = n0 + wc + cb * 16 + lr;
            const int h = col >> 6, d = col & 63;
            const float bcol = bias[col];
#pragma unroll
            for (int r = 0; r < 4; ++r) {
                const int row = m0 + wr + rb * 16 + q4 * 4 + r;
                const int b = row >> 11, k = row & 2047;
                hr[(((size_t)(b * 16 + h)) * 2048 + k) * 64 + d] = (bf16)(acc[rb][cb][r] + bcol);
            }
        }
    }
}

// ---------------------------------------------------------------- out GEMM
__global__ __launch_bounds__(256) void k_gemm_out(
    const bf16* __restrict__ attn, const bf16* __restrict__ Wt,
    const float* __restrict__ bias, float* __restrict__ out)
{
    __shared__ bf16 lds[2 * 128 * 32];
    f32x4 acc[4][4];
    const int m0 = blockIdx.x * 128, n0 = blockIdx.y * 128;
    gemm128_core(attn, Wt, 1024, m0, n0, lds, lds + 128 * 32, acc);

    const int lane = threadIdx.x & 63, wave = threadIdx.x >> 6;
    const int wr = (wave >> 1) * 64, wc = (wave & 1) * 64;
    const int lr = lane & 15, q4 = lane >> 4;
#pragma unroll
    for (int rb = 0; rb < 4; ++rb) {
#pragma unroll
        for (int cb = 0; cb < 4; ++cb) {
            const int col = n0 + wc + cb * 16 + lr;
            const float bcol = bias[col];
#pragma unroll
            for (int r = 0; r < 4; ++r) {
                const int row = m0 + wr + rb * 16 + q4 * 4 + r;
                out[(size_t)row * 1024 + col] = acc[rb][cb][r] + bcol;
            }
        }
    }
}

// ------------------------------------------------- fused attention, K-split
// Grid (16 q-tiles, 32 bh, 4 K-chunks). Each block computes unnormalized
// partial O and partial l over its contiguous K-tile range; k_attn_reduce
// combines (valid because no online max -- R8-verified).
// U slab strides: BD view 134 (write ~free, read ~2-way), Ps view 76
// (write conflict-free, read 2-way-free). Slab 2144 elems/wave.
// LDS 54016 B -> 3 blocks/CU.
__global__ __launch_bounds__(256) void k_attn_part(
    const bf16* __restrict__ hq_u, const bf16* __restrict__ hq_v,
    const bf16* __restrict__ hk, const bf16* __restrict__ hv,
    const bf16* __restrict__ hr,
    float* __restrict__ Opart, float* __restrict__ lpart)
{
    __shared__ bf16 Ks[64][72];        // K tile [k][d]
    __shared__ bf16 Vt[64][72];        // V tile transposed [d][k]
    __shared__ bf16 Rs[128][72];       // R band [j - j0][d]
    __shared__ bf16 U[4][2144];        // per-wave: BD view [16][134] / Ps view [16][76]

    const int bh = blockIdx.y;
    const int qt = blockIdx.x;
    const int chunk = blockIdx.z;
    const int q0 = qt * 64;
    const int tid = threadIdx.x, lane = tid & 63, wave = tid >> 6;
    const int lr = lane & 15, q4 = lane >> 4;
    bf16* Uw = &U[wave][0];

    // tile range for this chunk: kmax = 1024 + q0 + 64 -> nt = 17 + qt tiles
    const int nt = 17 + qt;
    const int t0 = (nt * chunk) >> 2;
    const int t1 = (nt * (chunk + 1)) >> 2;

    // Q fragments (A-operand layout: m = lane&15, k = (lane>>4)*8 + j)
    const size_t qrow = ((size_t)bh * 1024 + q0 + wave * 16 + lr) * 64;
    const bf16x8 qu0 = *(const bf16x8*)&hq_u[qrow + q4 * 8];
    const bf16x8 qu1 = *(const bf16x8*)&hq_u[qrow + 32 + q4 * 8];
    const bf16x8 qv0 = *(const bf16x8*)&hq_v[qrow + q4 * 8];
    const bf16x8 qv1 = *(const bf16x8*)&hq_v[qrow + 32 + q4 * 8];

    f32x4 Oacc[4];
#pragma unroll
    for (int i = 0; i < 4; ++i) { Oacc[i][0] = 0.f; Oacc[i][1] = 0.f; Oacc[i][2] = 0.f; Oacc[i][3] = 0.f; }
    float lp[4] = {0.f, 0.f, 0.f, 0.f};

    const size_t kvbase = (size_t)bh * 2048 * 64;

    for (int t = t0; t < t1; ++t) {
        const int k0 = t * 64;
        // ---- stage K tile
#pragma unroll
        for (int p = 0; p < 2; ++p) {
            const int ci = p * 256 + tid;
            const int krow = ci >> 3, cg = (ci & 7) * 8;
            *(bf16x8*)&Ks[krow][cg] = *(const bf16x8*)&hk[kvbase + (size_t)(k0 + krow) * 64 + cg];
        }
        // ---- stage V transposed
        {
            const int kk = (tid & 31) * 2, dbase = (tid >> 5) * 8;
            const bf16x8 a0 = *(const bf16x8*)&hv[kvbase + (size_t)(k0 + kk) * 64 + dbase];
            const bf16x8 a1 = *(const bf16x8*)&hv[kvbase + (size_t)(k0 + kk + 1) * 64 + dbase];
#pragma unroll
            for (int j = 0; j < 8; ++j) {
                bf16x2 t2; t2[0] = a0[j]; t2[1] = a1[j];
                *(bf16x2*)&Vt[dbase + j][kk] = t2;
            }
        }
        // ---- stage R band, rows j0..j0+127 (zero past K=2048)
        {
            const int j0 = k0 + 1024 - q0 - 64;
#pragma unroll
            for (int p = 0; p < 4; ++p) {
                const int ci = p * 256 + tid;
                const int jrow = ci >> 3, cg = (ci & 7) * 8;
                const int j = j0 + jrow;
                bf16x8 val;
#pragma unroll
                for (int z = 0; z < 8; ++z) val[z] = (bf16)0.f;
                if (j < 2048) val = *(const bf16x8*)&hr[kvbase + (size_t)j * 64 + cg];
                *(bf16x8*)&Rs[jrow][cg] = val;
            }
        }
        __syncthreads();

        // ---- AC = (hq+u) @ K^T
        f32x4 S[4];
#pragma unroll
        for (int cb = 0; cb < 4; ++cb) {
            const bf16x8 kf0 = *(const bf16x8*)&Ks[cb * 16 + lr][q4 * 8];
            const bf16x8 kf1 = *(const bf16x8*)&Ks[cb * 16 + lr][32 + q4 * 8];
            f32x4 z; z[0] = 0.f; z[1] = 0.f; z[2] = 0.f; z[3] = 0.f;
            z = __builtin_amdgcn_mfma_f32_16x16x32_bf16(qu0, kf0, z, 0, 0, 0);
            S[cb] = __builtin_amdgcn_mfma_f32_16x16x32_bf16(qu1, kf1, z, 0, 0, 0);
        }
        // ---- BD band -> LDS (BD view, stride 134)
#pragma unroll
        for (int jbi = 0; jbi < 5; ++jbi) {
            const int jb = jbi + 3 - wave;
            const bf16x8 rf0 = *(const bf16x8*)&Rs[jb * 16 + lr][q4 * 8];
            const bf16x8 rf1 = *(const bf16x8*)&Rs[jb * 16 + lr][32 + q4 * 8];
            f32x4 z; z[0] = 0.f; z[1] = 0.f; z[2] = 0.f; z[3] = 0.f;
            z = __builtin_amdgcn_mfma_f32_16x16x32_bf16(qv0, rf0, z, 0, 0, 0);
            z = __builtin_amdgcn_mfma_f32_16x16x32_bf16(qv1, rf1, z, 0, 0, 0);
#pragma unroll
            for (int r = 0; r < 4; ++r) Uw[(q4 * 4 + r) * 134 + jb * 16 + lr] = (bf16)z[r];
        }

        // ---- read ALL shifted BD values into registers (before Ps writes)
        float bdv[4][4];
#pragma unroll
        for (int cb = 0; cb < 4; ++cb)
#pragma unroll
            for (int r = 0; r < 4; ++r) {
                const int jj = cb * 16 + lr + 63 - wave * 16 - q4 * 4 - r;
                bdv[cb][r] = (float)Uw[(q4 * 4 + r) * 134 + jj];
            }

        // ---- scores: mask, exp (no max), accumulate l, Ps write (stride 76)
#pragma unroll
        for (int cb = 0; cb < 4; ++cb) {
            const int k = k0 + cb * 16 + lr;
#pragma unroll
            for (int r = 0; r < 4; ++r) {
                const int q = q0 + wave * 16 + q4 * 4 + r;
                const float s = (S[cb][r] + bdv[cb][r]) * 0.125f;
                const float p = (k <= 1024 + q) ? __expf(s) : 0.f;
                lp[r] += p;
                Uw[(q4 * 4 + r) * 76 + cb * 16 + lr] = (bf16)p;   // Ps view
            }
        }

        // ---- PV: P (A-layout via Ps view) @ V
        const bf16x8 pf0 = *(const bf16x8*)&Uw[lr * 76 + q4 * 8];
        const bf16x8 pf1 = *(const bf16x8*)&Uw[lr * 76 + 32 + q4 * 8];
#pragma unroll
        for (int db = 0; db < 4; ++db) {
            const bf16x8 vf0 = *(const bf16x8*)&Vt[db * 16 + lr][q4 * 8];
            const bf16x8 vf1 = *(const bf16x8*)&Vt[db * 16 + lr][32 + q4 * 8];
            Oacc[db] = __builtin_amdgcn_mfma_f32_16x16x32_bf16(pf0, vf0, Oacc[db], 0, 0, 0);
            Oacc[db] = __builtin_amdgcn_mfma_f32_16x16x32_bf16(pf1, vf1, Oacc[db], 0, 0, 0);
        }
        __syncthreads();
    }

    // ---- 16-lane row-sum of l, write partials
#pragma unroll
    for (int off = 1; off < 16; off <<= 1)
#pragma unroll
        for (int r = 0; r < 4; ++r) lp[r] += __shfl_xor(lp[r], off, 64);

    const size_t prow = ((size_t)chunk * 32 + bh) * 1024 + q0 + wave * 16;
#pragma unroll
    for (int r = 0; r < 4; ++r) {
        const int ql = q4 * 4 + r;
#pragma unroll
        for (int db = 0; db < 4; ++db)
            Opart[(prow + ql) * 64 + db * 16 + lr] = Oacc[db][r];
        if (lr == 0) lpart[prow + ql] = lp[r];
    }
}

// --------------------------------------------------- combine K-split partials
// One thread per 4 output elems. attn[b][q][h*64+d] = sum_c O_c / sum_c l_c.
__global__ __launch_bounds__(256) void k_attn_reduce(
    const float* __restrict__ Opart, const float* __restrict__ lpart,
    bf16* __restrict__ attn)
{
    const int i   = blockIdx.x * 256 + threadIdx.x;   // 524288 threads
    const int row = i >> 4;                           // bh*1024 + q
    const int dof = (i & 15) * 4;
    f32x4 o; o[0] = 0.f; o[1] = 0.f; o[2] = 0.f; o[3] = 0.f;
    float l = 0.f;
#pragma unroll
    for (int c = 0; c < 4; ++c) {
        o += *(const f32x4*)&Opart[((size_t)(c * 32768 + row)) * 64 + dof];
        l += lpart[c * 32768 + row];
    }
    const float rl = 1.f / l;
    const int bh = row >> 10, q = row & 1023;
    const int b = bh >> 4, h = bh & 15;
    bf16x4 out;
#pragma unroll
    for (int j = 0; j < 4; ++j) out[j] = (bf16)(o[j] * rl);
    *(bf16x4*)&attn[(((size_t)b * 1024 + q) * 16 + h) * 64 + dof] = out;
}

// ------------------------------------------------------------------ launch
extern "C" void kernel_launch(void* const* d_in, const int* in_sizes, int n_in,
                              void* d_out, int out_size, void* d_ws, size_t ws_size,
                              hipStream_t stream)
{
    const float* inputs = (const float*)d_in[0];
    const float* mem    = (const float*)d_in[1];
    const float* r      = (const float*)d_in[2];
    const float* W_qkv  = (const float*)d_in[3];
    const float* b_qkv  = (const float*)d_in[4];
    const float* W_r    = (const float*)d_in[5];
    const float* b_r    = (const float*)d_in[6];
    const float* W_o    = (const float*)d_in[7];
    const float* b_o    = (const float*)d_in[8];
    const float* u      = (const float*)d_in[9];
    const float* v      = (const float*)d_in[10];
    float* out = (float*)d_out;

    char* ws = (char*)d_ws;
    size_t off = 0;
    auto alloc = [&](size_t bytes) -> void* {
        void* p = ws + off;
        off += (bytes + 255) & ~(size_t)255;
        return p;
    };
    // ---- persistent region (live across attn phase)
    bf16* hq_u  = (bf16*)alloc(2ull * 16 * 1024 * 64 * 2);
    bf16* hq_v  = (bf16*)alloc(2ull * 16 * 1024 * 64 * 2);
    bf16* hk    = (bf16*)alloc(2ull * 16 * 2048 * 64 * 2);
    bf16* hv    = (bf16*)alloc(2ull * 16 * 2048 * 64 * 2);
    bf16* hr    = (bf16*)alloc(2ull * 16 * 2048 * 64 * 2);
    bf16* attnb = (bf16*)alloc(2ull * 1024 * 1024 * 2);
    bf16* Wot   = (bf16*)alloc(1024ull * 1024 * 2);
    // ---- union region: prep buffers (dead before attn) / attn partials
    char* un = ws + off;
    bf16* catb  = (bf16*)un;                         // 8.39 MB
    bf16* rb    = catb + 4096ull * 1024;             // 8.39 MB
    bf16* Wqkvt = rb + 4096ull * 1024;               // 6.29 MB
    bf16* Wrt   = Wqkvt + 3072ull * 1024;            // 2.10 MB
    float* Opart = (float*)un;                       // 4*32*1024*64*4 = 33.55 MB
    float* lpart = (float*)(un + 4ull * 32 * 1024 * 64 * 4);  // 0.52 MB

    k_tcast<<<dim3(96, 32), 256, 0, stream>>>(W_qkv, Wqkvt, 1024, 3072);
    k_tcast<<<dim3(32, 32), 256, 0, stream>>>(W_r, Wrt, 1024, 1024);
    k_tcast<<<dim3(32, 32), 256, 0, stream>>>(W_o, Wot, 1024, 1024);
    k_cast_cat<<<4096, 256, 0, stream>>>(mem, inputs, catb);
    k_cast<<<4096, 256, 0, stream>>>(r, rb);

    k_gemm_qkv<<<dim3(32, 24), 256, 0, stream>>>(catb, Wqkvt, b_qkv, u, v, hq_u, hq_v, hk, hv);
    k_gemm_r<<<dim3(32, 8), 256, 0, stream>>>(rb, Wrt, b_r, hr);
    k_attn_part<<<dim3(16, 32, 4), 256, 0, stream>>>(hq_u, hq_v, hk, hv, hr, Opart, lpart);
    k_attn_reduce<<<2048, 256, 0, stream>>>(Opart, lpart, attnb);
    k_gemm_out<<<dim3(16, 8), 256, 0, stream>>>(attnb, Wot, b_o, out);
}

// Round 10
// 317.611 us; speedup vs baseline: 1.0392x; 1.0392x over previous
//
#include <hip/hip_runtime.h>
#include <hip/hip_bf16.h>
#include <stdint.h>

// Transformer-XL relative MHA on MI355X (gfx950), bf16 MFMA pipeline.
// B=2, Q=1024, M=1024, D=1024, H=16, DH=64, K=2048.
// Buffers are fp32 (reference dtypes); checker threshold 1.38e-3.
// Evidence log:
//  - async global_load_lds GEMM staging verified (R5==R6 identity, R7/R8 pass).
//  - R5 failure isolated to bpermute block-selection (banned).
//  - R9: K-split x4 regressed -- occupancy stuck ~16% (LDS 54272x3 within 1KB
//    of the 160KiB pool => residency stayed 2/CU) + split overhead. R10:
//    LDS 47616 (3x = 143KB, 20KB slack), chunks x2, V pre-transposed.

typedef __bf16 bf16;
typedef __bf16 bf16x2 __attribute__((ext_vector_type(2)));
typedef __bf16 bf16x4 __attribute__((ext_vector_type(4)));
typedef __bf16 bf16x8 __attribute__((ext_vector_type(8)));
typedef float  f32x4  __attribute__((ext_vector_type(4)));

// ---------------------------------------------------------------- async copy
__device__ __forceinline__ void async_copy16(void* lds, const void* g) {
    auto gp = (const __attribute__((address_space(1))) void*)(uintptr_t)g;
    auto lp = (__attribute__((address_space(3))) void*)(uint32_t)(uintptr_t)lds;
    __builtin_amdgcn_global_load_lds(gp, lp, 16, 0, 0);
}

// ------------------------------------------------------- 128x128 GEMM core
// C[128,128] = A[m0:+128, :Kd] * Bt[n0:+128, :Kd]^T   (both bf16, K contiguous)
// acc[rb][cb] C-layout: row = m0 + wr + rb*16 + (lane>>4)*4 + reg,
//                       col = n0 + wc + cb*16 + (lane&15)
__device__ __forceinline__ void gemm128_core(
    const bf16* __restrict__ A, const bf16* __restrict__ Bt, const int Kd,
    const int m0, const int n0, bf16* As, bf16* Bs, f32x4 acc[4][4])
{
    const int tid  = threadIdx.x;
    const int lane = tid & 63;
    const int wave = tid >> 6;
    const int wr   = (wave >> 1) * 64;
    const int wc   = (wave & 1) * 64;
    const int lr   = lane & 15;
    const int q4   = lane >> 4;

#pragma unroll
    for (int i = 0; i < 4; ++i)
#pragma unroll
        for (int j = 0; j < 4; ++j) {
            acc[i][j][0] = 0.f; acc[i][j][1] = 0.f; acc[i][j][2] = 0.f; acc[i][j][3] = 0.f;
        }

    for (int k0 = 0; k0 < Kd; k0 += 32) {
#pragma unroll
        for (int it = 0; it < 2; ++it) {
            const int cb0   = (it * 4 + wave) * 64;   // wave-uniform chunk base
            const int chunk = cb0 + lane;
            const int row   = chunk >> 2;
            const int cg    = (chunk & 3) * 8;
            async_copy16(As + cb0 * 8, A  + (size_t)(m0 + row) * Kd + k0 + cg);
            async_copy16(Bs + cb0 * 8, Bt + (size_t)(n0 + row) * Kd + k0 + cg);
        }
        __syncthreads();
        bf16x8 af[4], bfr[4];
#pragma unroll
        for (int rb = 0; rb < 4; ++rb)
            af[rb] = *(const bf16x8*)&As[(wr + rb * 16 + lr) * 32 + q4 * 8];
#pragma unroll
        for (int cb = 0; cb < 4; ++cb)
            bfr[cb] = *(const bf16x8*)&Bs[(wc + cb * 16 + lr) * 32 + q4 * 8];
#pragma unroll
        for (int rb = 0; rb < 4; ++rb)
#pragma unroll
            for (int cb = 0; cb < 4; ++cb)
                acc[rb][cb] = __builtin_amdgcn_mfma_f32_16x16x32_bf16(af[rb], bfr[cb], acc[rb][cb], 0, 0, 0);
        __syncthreads();
    }
}

// ------------------------------------------------------------- prep kernels
__global__ __launch_bounds__(256) void k_tcast(const float* __restrict__ in,
                                               bf16* __restrict__ out, int R, int C)
{
    __shared__ float t[32][33];
    const int c0 = blockIdx.x * 32, r0 = blockIdx.y * 32;
    const int lc = threadIdx.x & 31, lrow = threadIdx.x >> 5;
#pragma unroll
    for (int p = 0; p < 4; ++p)
        t[lrow + p * 8][lc] = in[(size_t)(r0 + lrow + p * 8) * C + c0 + lc];
    __syncthreads();
#pragma unroll
    for (int p = 0; p < 4; ++p)
        out[(size_t)(c0 + lrow + p * 8) * R + r0 + lc] = (bf16)t[lc][lrow + p * 8];
}

__global__ __launch_bounds__(256) void k_cast_cat(const float* __restrict__ mem,
                                                  const float* __restrict__ inp,
                                                  bf16* __restrict__ catb)
{
    const int e   = (blockIdx.x * 256 + threadIdx.x) * 4;
    const int row = e >> 10, dc = e & 1023;
    const int b   = row >> 11, k = row & 2047;
    const float* src = (k < 1024) ? mem + ((size_t)b * 1024 + k) * 1024 + dc
                                  : inp + ((size_t)b * 1024 + (k - 1024)) * 1024 + dc;
    float4 f = *(const float4*)src;
    bf16x4 o; o[0] = (bf16)f.x; o[1] = (bf16)f.y; o[2] = (bf16)f.z; o[3] = (bf16)f.w;
    *(bf16x4*)&catb[e] = o;
}

__global__ __launch_bounds__(256) void k_cast(const float* __restrict__ in,
                                              bf16* __restrict__ out)
{
    const int e = (blockIdx.x * 256 + threadIdx.x) * 4;
    float4 f = *(const float4*)(in + e);
    bf16x4 o; o[0] = (bf16)f.x; o[1] = (bf16)f.y; o[2] = (bf16)f.z; o[3] = (bf16)f.w;
    *(bf16x4*)&out[e] = o;
}

// ---------------------------------------------------------------- QKV GEMM
// hv is written TRANSPOSED per head: hvT[bh][d][k]  (for direct Vt staging)
__global__ __launch_bounds__(256) void k_gemm_qkv(
    const bf16* __restrict__ catb, const bf16* __restrict__ Wt,
    const float* __restrict__ bias, const float* __restrict__ u, const float* __restrict__ v,
    bf16* __restrict__ hq_u, bf16* __restrict__ hq_v,
    bf16* __restrict__ hk, bf16* __restrict__ hvT)
{
    __shared__ bf16 lds[2 * 128 * 32];
    f32x4 acc[4][4];
    const int m0 = blockIdx.x * 128, n0 = blockIdx.y * 128;
    gemm128_core(catb, Wt, 1024, m0, n0, lds, lds + 128 * 32, acc);

    const int lane = threadIdx.x & 63, wave = threadIdx.x >> 6;
    const int wr = (wave >> 1) * 64, wc = (wave & 1) * 64;
    const int lr = lane & 15, q4 = lane >> 4;
#pragma unroll
    for (int rb = 0; rb < 4; ++rb) {
#pragma unroll
        for (int cb = 0; cb < 4; ++cb) {
            const int col  = n0 + wc + cb * 16 + lr;
            const int part = col >> 10;
            const int hd   = col & 1023;
            const int h    = hd >> 6, d = hd & 63;
            const float bcol = bias[col];
#pragma unroll
            for (int r = 0; r < 4; ++r) {
                const int row = m0 + wr + rb * 16 + q4 * 4 + r;
                const int b   = row >> 11, k = row & 2047;
                const float val = acc[rb][cb][r] + bcol;
                if (part == 0) {
                    if (k >= 1024) {
                        const size_t o = (((size_t)(b * 16 + h)) * 1024 + (k - 1024)) * 64 + d;
                        hq_u[o] = (bf16)(val + u[hd]);
                        hq_v[o] = (bf16)(val + v[hd]);
                    }
                } else if (part == 1) {
                    hvT[(((size_t)(b * 16 + h)) * 64 + d) * 2048 + k] = (bf16)val;
                } else {
                    hk[(((size_t)(b * 16 + h)) * 2048 + k) * 64 + d] = (bf16)val;
                }
            }
        }
    }
}

// ------------------------------------------------------------------ R GEMM
__global__ __launch_bounds__(256) void k_gemm_r(
    const bf16* __restrict__ rb_, const bf16* __restrict__ Wt,
    const float* __restrict__ bias, bf16* __restrict__ hr)
{
    __shared__ bf16 lds[2 * 128 * 32];
    f32x4 acc[4][4];
    const int m0 = blockIdx.x * 128, n0 = blockIdx.y * 128;
    gemm128_core(rb_, Wt, 1024, m0, n0, lds, lds + 128 * 32, acc);

    const int lane = threadIdx.x & 63, wave = threadIdx.x >> 6;
    const int wr = (wave >> 1) * 64, wc = (wave & 1) * 64;
    const int lr = lane & 15, q4 = lane >> 4;
#pragma unroll
    for (int rb = 0; rb < 4; ++rb) {
#pragma unroll
        for (int cb = 0; cb < 4; ++cb) {
            const int col = n0 + wc + cb * 16 + lr;
            const int h = col >> 6, d = col & 63;
            const float bcol = bias[col];
#pragma unroll
            for (int r = 0; r < 4; ++r) {
                const int row = m0 + wr + rb * 16 + q4 * 4 + r;
                const int b = row >> 11, k = row & 2047;
                hr[(((size_t)(b * 16 + h)) * 2048 + k) * 64 + d] = (bf16)(acc[rb][cb][r] + bcol);
            }
        }
    }
}

// ---------------------------------------------------------------- out GEMM
__global__ __launch_bounds__(256) void k_gemm_out(
    const bf16* __restrict__ attn, const bf16* __restrict__ Wt,
    const float* __restrict__ bias, float* __restrict__ out)
{
    __shared__ bf16 lds[2 * 128 * 32];
    f32x4 acc[4][4];
    const int m0 = blockIdx.x * 128, n0 = blockIdx.y * 128;
    gemm128_core(attn, Wt, 1024, m0, n0, lds, lds + 128 * 32, acc);

    const int lane = threadIdx.x & 63, wave = threadIdx.x >> 6;
    const int wr = (wave >> 1) * 64, wc = (wave & 1) * 64;
    const int lr = lane & 15, q4 = lane >> 4;
#pragma unroll
    for (int rb = 0; rb < 4; ++rb) {
#pragma unroll
        for (int cb = 0; cb < 4; ++cb) {
            const int col = n0 + wc + cb * 16 + lr;
            const float bcol = bias[col];
#pragma unroll
            for (int r = 0; r < 4; ++r) {
                const int row = m0 + wr + rb * 16 + q4 * 4 + r;
                out[(size_t)row * 1024 + col] = acc[rb][cb][r] + bcol;
            }
        }
    }
}

// ------------------------------------------------- fused attention, K-split
// Grid (16 q-tiles, 32 bh, 2 K-chunks). Unnormalized partials (no-online-max,
// R8-verified); k_attn_reduce combines.
// Compact BD view: ccol = cb*16 + lr + 15 - (q4*4+r) in [0,79) -- the wave
// term cancels. U slab/wave = max(16*84 BD, 16*76 Ps) = 1344 elems.
// LDS total 47616 B -> 3 blocks/CU with 20KB slack.
__global__ __launch_bounds__(256) void k_attn_part(
    const bf16* __restrict__ hq_u, const bf16* __restrict__ hq_v,
    const bf16* __restrict__ hk, const bf16* __restrict__ hvT,
    const bf16* __restrict__ hr,
    float* __restrict__ Opart, float* __restrict__ lpart)
{
    __shared__ bf16 Ks[64][72];        // K tile [k][d]
    __shared__ bf16 Vt[64][72];        // V tile [d][k] (pre-transposed global)
    __shared__ bf16 Rs[128][72];       // R band [j - j0][d]
    __shared__ bf16 U[4][1344];        // per-wave: BD view [16][84] / Ps view [16][76]

    const int bh = blockIdx.y;
    const int qt = blockIdx.x;
    const int chunk = blockIdx.z;
    const int q0 = qt * 64;
    const int tid = threadIdx.x, lane = tid & 63, wave = tid >> 6;
    const int lr = lane & 15, q4 = lane >> 4;
    bf16* Uw = &U[wave][0];

    // tile range: kmax = 1024 + q0 + 64 -> nt = 17 + qt tiles, split in 2
    const int nt = 17 + qt;
    const int t0 = (nt * chunk) >> 1;
    const int t1 = (nt * (chunk + 1)) >> 1;

    // Q fragments (A-operand layout: m = lane&15, k = (lane>>4)*8 + j)
    const size_t qrow = ((size_t)bh * 1024 + q0 + wave * 16 + lr) * 64;
    const bf16x8 qu0 = *(const bf16x8*)&hq_u[qrow + q4 * 8];
    const bf16x8 qu1 = *(const bf16x8*)&hq_u[qrow + 32 + q4 * 8];
    const bf16x8 qv0 = *(const bf16x8*)&hq_v[qrow + q4 * 8];
    const bf16x8 qv1 = *(const bf16x8*)&hq_v[qrow + 32 + q4 * 8];

    f32x4 Oacc[4];
#pragma unroll
    for (int i = 0; i < 4; ++i) { Oacc[i][0] = 0.f; Oacc[i][1] = 0.f; Oacc[i][2] = 0.f; Oacc[i][3] = 0.f; }
    float lp[4] = {0.f, 0.f, 0.f, 0.f};

    const size_t kvbase = (size_t)bh * 2048 * 64;

    for (int t = t0; t < t1; ++t) {
        const int k0 = t * 64;
        // ---- stage K tile [k][d] and V tile [d][k]: 2 b128 copies each
#pragma unroll
        for (int p = 0; p < 2; ++p) {
            const int ci = p * 256 + tid;
            const int rrow = ci >> 3, cg = (ci & 7) * 8;
            *(bf16x8*)&Ks[rrow][cg] = *(const bf16x8*)&hk [kvbase + (size_t)(k0 + rrow) * 64 + cg];
            *(bf16x8*)&Vt[rrow][cg] = *(const bf16x8*)&hvT[kvbase + (size_t)rrow * 2048 + k0 + cg];
        }
        // ---- stage R band, rows j0..j0+127 (zero past K=2048)
        {
            const int j0 = k0 + 1024 - q0 - 64;
#pragma unroll
            for (int p = 0; p < 4; ++p) {
                const int ci = p * 256 + tid;
                const int jrow = ci >> 3, cg = (ci & 7) * 8;
                const int j = j0 + jrow;
                bf16x8 val;
#pragma unroll
                for (int z = 0; z < 8; ++z) val[z] = (bf16)0.f;
                if (j < 2048) val = *(const bf16x8*)&hr[kvbase + (size_t)j * 64 + cg];
                *(bf16x8*)&Rs[jrow][cg] = val;
            }
        }
        __syncthreads();

        // ---- AC = (hq+u) @ K^T
        f32x4 S[4];
#pragma unroll
        for (int cb = 0; cb < 4; ++cb) {
            const bf16x8 kf0 = *(const bf16x8*)&Ks[cb * 16 + lr][q4 * 8];
            const bf16x8 kf1 = *(const bf16x8*)&Ks[cb * 16 + lr][32 + q4 * 8];
            f32x4 z; z[0] = 0.f; z[1] = 0.f; z[2] = 0.f; z[3] = 0.f;
            z = __builtin_amdgcn_mfma_f32_16x16x32_bf16(qu0, kf0, z, 0, 0, 0);
            S[cb] = __builtin_amdgcn_mfma_f32_16x16x32_bf16(qu1, kf1, z, 0, 0, 0);
        }
        // ---- BD band -> compact LDS view (stride 84, col jbi*16+lr)
#pragma unroll
        for (int jbi = 0; jbi < 5; ++jbi) {
            const int jb = jbi + 3 - wave;
            const bf16x8 rf0 = *(const bf16x8*)&Rs[jb * 16 + lr][q4 * 8];
            const bf16x8 rf1 = *(const bf16x8*)&Rs[jb * 16 + lr][32 + q4 * 8];
            f32x4 z; z[0] = 0.f; z[1] = 0.f; z[2] = 0.f; z[3] = 0.f;
            z = __builtin_amdgcn_mfma_f32_16x16x32_bf16(qv0, rf0, z, 0, 0, 0);
            z = __builtin_amdgcn_mfma_f32_16x16x32_bf16(qv1, rf1, z, 0, 0, 0);
#pragma unroll
            for (int r = 0; r < 4; ++r) Uw[(q4 * 4 + r) * 84 + jbi * 16 + lr] = (bf16)z[r];
        }

        // ---- read ALL shifted BD values into registers (before Ps writes)
        float bdv[4][4];
#pragma unroll
        for (int cb = 0; cb < 4; ++cb)
#pragma unroll
            for (int r = 0; r < 4; ++r) {
                const int tq = q4 * 4 + r;
                bdv[cb][r] = (float)Uw[tq * 84 + cb * 16 + lr + 15 - tq];
            }

        // ---- scores: mask, exp (no max), accumulate l, Ps write (stride 76)
#pragma unroll
        for (int cb = 0; cb < 4; ++cb) {
            const int k = k0 + cb * 16 + lr;
#pragma unroll
            for (int r = 0; r < 4; ++r) {
                const int q = q0 + wave * 16 + q4 * 4 + r;
                const float s = (S[cb][r] + bdv[cb][r]) * 0.125f;
                const float p = (k <= 1024 + q) ? __expf(s) : 0.f;
                lp[r] += p;
                Uw[(q4 * 4 + r) * 76 + cb * 16 + lr] = (bf16)p;   // Ps view
            }
        }

        // ---- PV: P (A-layout via Ps view) @ V
        const bf16x8 pf0 = *(const bf16x8*)&Uw[lr * 76 + q4 * 8];
        const bf16x8 pf1 = *(const bf16x8*)&Uw[lr * 76 + 32 + q4 * 8];
#pragma unroll
        for (int db = 0; db < 4; ++db) {
            const bf16x8 vf0 = *(const bf16x8*)&Vt[db * 16 + lr][q4 * 8];
            const bf16x8 vf1 = *(const bf16x8*)&Vt[db * 16 + lr][32 + q4 * 8];
            Oacc[db] = __builtin_amdgcn_mfma_f32_16x16x32_bf16(pf0, vf0, Oacc[db], 0, 0, 0);
            Oacc[db] = __builtin_amdgcn_mfma_f32_16x16x32_bf16(pf1, vf1, Oacc[db], 0, 0, 0);
        }
        __syncthreads();
    }

    // ---- 16-lane row-sum of l, write partials
#pragma unroll
    for (int off = 1; off < 16; off <<= 1)
#pragma unroll
        for (int r = 0; r < 4; ++r) lp[r] += __shfl_xor(lp[r], off, 64);

    const size_t prow = ((size_t)chunk * 32 + bh) * 1024 + q0 + wave * 16;
#pragma unroll
    for (int r = 0; r < 4; ++r) {
        const int ql = q4 * 4 + r;
#pragma unroll
        for (int db = 0; db < 4; ++db)
            Opart[(prow + ql) * 64 + db * 16 + lr] = Oacc[db][r];
        if (lr == 0) lpart[prow + ql] = lp[r];
    }
}

// --------------------------------------------------- combine K-split partials
__global__ __launch_bounds__(256) void k_attn_reduce(
    const float* __restrict__ Opart, const float* __restrict__ lpart,
    bf16* __restrict__ attn)
{
    const int i   = blockIdx.x * 256 + threadIdx.x;   // 524288 threads
    const int row = i >> 4;                           // bh*1024 + q
    const int dof = (i & 15) * 4;
    f32x4 o; o[0] = 0.f; o[1] = 0.f; o[2] = 0.f; o[3] = 0.f;
    float l = 0.f;
#pragma unroll
    for (int c = 0; c < 2; ++c) {
        o += *(const f32x4*)&Opart[((size_t)(c * 32768 + row)) * 64 + dof];
        l += lpart[c * 32768 + row];
    }
    const float rl = 1.f / l;
    const int bh = row >> 10, q = row & 1023;
    const int b = bh >> 4, h = bh & 15;
    bf16x4 out;
#pragma unroll
    for (int j = 0; j < 4; ++j) out[j] = (bf16)(o[j] * rl);
    *(bf16x4*)&attn[(((size_t)b * 1024 + q) * 16 + h) * 64 + dof] = out;
}

// ------------------------------------------------------------------ launch
extern "C" void kernel_launch(void* const* d_in, const int* in_sizes, int n_in,
                              void* d_out, int out_size, void* d_ws, size_t ws_size,
                              hipStream_t stream)
{
    const float* inputs = (const float*)d_in[0];
    const float* mem    = (const float*)d_in[1];
    const float* r      = (const float*)d_in[2];
    const float* W_qkv  = (const float*)d_in[3];
    const float* b_qkv  = (const float*)d_in[4];
    const float* W_r    = (const float*)d_in[5];
    const float* b_r    = (const float*)d_in[6];
    const float* W_o    = (const float*)d_in[7];
    const float* b_o    = (const float*)d_in[8];
    const float* u      = (const float*)d_in[9];
    const float* v      = (const float*)d_in[10];
    float* out = (float*)d_out;

    char* ws = (char*)d_ws;
    size_t off = 0;
    auto alloc = [&](size_t bytes) -> void* {
        void* p = ws + off;
        off += (bytes + 255) & ~(size_t)255;
        return p;
    };
    // ---- persistent region (live across attn phase)
    bf16* hq_u  = (bf16*)alloc(2ull * 16 * 1024 * 64 * 2);
    bf16* hq_v  = (bf16*)alloc(2ull * 16 * 1024 * 64 * 2);
    bf16* hk    = (bf16*)alloc(2ull * 16 * 2048 * 64 * 2);
    bf16* hvT   = (bf16*)alloc(2ull * 16 * 2048 * 64 * 2);
    bf16* hr    = (bf16*)alloc(2ull * 16 * 2048 * 64 * 2);
    bf16* attnb = (bf16*)alloc(2ull * 1024 * 1024 * 2);
    bf16* Wot   = (bf16*)alloc(1024ull * 1024 * 2);
    // ---- union region: prep buffers (dead before attn) / attn partials
    char* un = ws + off;
    bf16* catb  = (bf16*)un;                         // 8.39 MB
    bf16* rb    = catb + 4096ull * 1024;             // 8.39 MB
    bf16* Wqkvt = rb + 4096ull * 1024;               // 6.29 MB
    bf16* Wrt   = Wqkvt + 3072ull * 1024;            // 2.10 MB
    float* Opart = (float*)un;                       // 2*32*1024*64*4 = 16.78 MB
    float* lpart = (float*)(un + 2ull * 32 * 1024 * 64 * 4);  // 0.26 MB

    k_tcast<<<dim3(96, 32), 256, 0, stream>>>(W_qkv, Wqkvt, 1024, 3072);
    k_tcast<<<dim3(32, 32), 256, 0, stream>>>(W_r, Wrt, 1024, 1024);
    k_tcast<<<dim3(32, 32), 256, 0, stream>>>(W_o, Wot, 1024, 1024);
    k_cast_cat<<<4096, 256, 0, stream>>>(mem, inputs, catb);
    k_cast<<<4096, 256, 0, stream>>>(r, rb);

    k_gemm_qkv<<<dim3(32, 24), 256, 0, stream>>>(catb, Wqkvt, b_qkv, u, v, hq_u, hq_v, hk, hvT);
    k_gemm_r<<<dim3(32, 8), 256, 0, stream>>>(rb, Wrt, b_r, hr);
    k_attn_part<<<dim3(16, 32, 2), 256, 0, stream>>>(hq_u, hq_v, hk, hvT, hr, Opart, lpart);
    k_attn_reduce<<<2048, 256, 0, stream>>>(Opart, lpart, attnb);
    k_gemm_out<<<dim3(16, 8), 256, 0, stream>>>(attnb, Wot, b_o, out);
}

// Round 11
// 304.947 us; speedup vs baseline: 1.0824x; 1.0415x over previous
//
#include <hip/hip_runtime.h>
#include <hip/hip_bf16.h>
#include <stdint.h>

// Transformer-XL relative MHA on MI355X (gfx950), bf16 MFMA pipeline.
// B=2, Q=1024, M=1024, D=1024, H=16, DH=64, K=2048.
// Buffers are fp32 (reference dtypes); checker threshold 1.38e-3.
// Evidence log:
//  - async global_load_lds GEMM staging verified (R5==R6 identity, R7/R8 pass).
//  - R5 failure isolated to bpermute block-selection (banned).
//  - R9/R10: K-split regressed both times; occupancy pinned ~2 blocks/CU
//    regardless of LDS (never the binding limit). Split reverted.
//  - R10 verified: compact-U layout, hvT pre-transpose (kept).
//  - R11: register-prefetch software pipelining in the attn K-loop to hide
//    exposed global-load latency (MfmaUtil+VALUBusy was only ~31%).

typedef __bf16 bf16;
typedef __bf16 bf16x2 __attribute__((ext_vector_type(2)));
typedef __bf16 bf16x4 __attribute__((ext_vector_type(4)));
typedef __bf16 bf16x8 __attribute__((ext_vector_type(8)));
typedef float  f32x4  __attribute__((ext_vector_type(4)));

// ---------------------------------------------------------------- async copy
__device__ __forceinline__ void async_copy16(void* lds, const void* g) {
    auto gp = (const __attribute__((address_space(1))) void*)(uintptr_t)g;
    auto lp = (__attribute__((address_space(3))) void*)(uint32_t)(uintptr_t)lds;
    __builtin_amdgcn_global_load_lds(gp, lp, 16, 0, 0);
}

// ------------------------------------------------------- 128x128 GEMM core
// C[128,128] = A[m0:+128, :Kd] * Bt[n0:+128, :Kd]^T   (both bf16, K contiguous)
// acc[rb][cb] C-layout: row = m0 + wr + rb*16 + (lane>>4)*4 + reg,
//                       col = n0 + wc + cb*16 + (lane&15)
__device__ __forceinline__ void gemm128_core(
    const bf16* __restrict__ A, const bf16* __restrict__ Bt, const int Kd,
    const int m0, const int n0, bf16* As, bf16* Bs, f32x4 acc[4][4])
{
    const int tid  = threadIdx.x;
    const int lane = tid & 63;
    const int wave = tid >> 6;
    const int wr   = (wave >> 1) * 64;
    const int wc   = (wave & 1) * 64;
    const int lr   = lane & 15;
    const int q4   = lane >> 4;

#pragma unroll
    for (int i = 0; i < 4; ++i)
#pragma unroll
        for (int j = 0; j < 4; ++j) {
            acc[i][j][0] = 0.f; acc[i][j][1] = 0.f; acc[i][j][2] = 0.f; acc[i][j][3] = 0.f;
        }

    for (int k0 = 0; k0 < Kd; k0 += 32) {
#pragma unroll
        for (int it = 0; it < 2; ++it) {
            const int cb0   = (it * 4 + wave) * 64;   // wave-uniform chunk base
            const int chunk = cb0 + lane;
            const int row   = chunk >> 2;
            const int cg    = (chunk & 3) * 8;
            async_copy16(As + cb0 * 8, A  + (size_t)(m0 + row) * Kd + k0 + cg);
            async_copy16(Bs + cb0 * 8, Bt + (size_t)(n0 + row) * Kd + k0 + cg);
        }
        __syncthreads();
        bf16x8 af[4], bfr[4];
#pragma unroll
        for (int rb = 0; rb < 4; ++rb)
            af[rb] = *(const bf16x8*)&As[(wr + rb * 16 + lr) * 32 + q4 * 8];
#pragma unroll
        for (int cb = 0; cb < 4; ++cb)
            bfr[cb] = *(const bf16x8*)&Bs[(wc + cb * 16 + lr) * 32 + q4 * 8];
#pragma unroll
        for (int rb = 0; rb < 4; ++rb)
#pragma unroll
            for (int cb = 0; cb < 4; ++cb)
                acc[rb][cb] = __builtin_amdgcn_mfma_f32_16x16x32_bf16(af[rb], bfr[cb], acc[rb][cb], 0, 0, 0);
        __syncthreads();
    }
}

// ------------------------------------------------------------- prep kernels
__global__ __launch_bounds__(256) void k_tcast(const float* __restrict__ in,
                                               bf16* __restrict__ out, int R, int C)
{
    __shared__ float t[32][33];
    const int c0 = blockIdx.x * 32, r0 = blockIdx.y * 32;
    const int lc = threadIdx.x & 31, lrow = threadIdx.x >> 5;
#pragma unroll
    for (int p = 0; p < 4; ++p)
        t[lrow + p * 8][lc] = in[(size_t)(r0 + lrow + p * 8) * C + c0 + lc];
    __syncthreads();
#pragma unroll
    for (int p = 0; p < 4; ++p)
        out[(size_t)(c0 + lrow + p * 8) * R + r0 + lc] = (bf16)t[lc][lrow + p * 8];
}

__global__ __launch_bounds__(256) void k_cast_cat(const float* __restrict__ mem,
                                                  const float* __restrict__ inp,
                                                  bf16* __restrict__ catb)
{
    const int e   = (blockIdx.x * 256 + threadIdx.x) * 4;
    const int row = e >> 10, dc = e & 1023;
    const int b   = row >> 11, k = row & 2047;
    const float* src = (k < 1024) ? mem + ((size_t)b * 1024 + k) * 1024 + dc
                                  : inp + ((size_t)b * 1024 + (k - 1024)) * 1024 + dc;
    float4 f = *(const float4*)src;
    bf16x4 o; o[0] = (bf16)f.x; o[1] = (bf16)f.y; o[2] = (bf16)f.z; o[3] = (bf16)f.w;
    *(bf16x4*)&catb[e] = o;
}

__global__ __launch_bounds__(256) void k_cast(const float* __restrict__ in,
                                              bf16* __restrict__ out)
{
    const int e = (blockIdx.x * 256 + threadIdx.x) * 4;
    float4 f = *(const float4*)(in + e);
    bf16x4 o; o[0] = (bf16)f.x; o[1] = (bf16)f.y; o[2] = (bf16)f.z; o[3] = (bf16)f.w;
    *(bf16x4*)&out[e] = o;
}

// ---------------------------------------------------------------- QKV GEMM
// hv is written TRANSPOSED per head: hvT[bh][d][k]  (for direct Vt staging)
__global__ __launch_bounds__(256) void k_gemm_qkv(
    const bf16* __restrict__ catb, const bf16* __restrict__ Wt,
    const float* __restrict__ bias, const float* __restrict__ u, const float* __restrict__ v,
    bf16* __restrict__ hq_u, bf16* __restrict__ hq_v,
    bf16* __restrict__ hk, bf16* __restrict__ hvT)
{
    __shared__ bf16 lds[2 * 128 * 32];
    f32x4 acc[4][4];
    const int m0 = blockIdx.x * 128, n0 = blockIdx.y * 128;
    gemm128_core(catb, Wt, 1024, m0, n0, lds, lds + 128 * 32, acc);

    const int lane = threadIdx.x & 63, wave = threadIdx.x >> 6;
    const int wr = (wave >> 1) * 64, wc = (wave & 1) * 64;
    const int lr = lane & 15, q4 = lane >> 4;
#pragma unroll
    for (int rb = 0; rb < 4; ++rb) {
#pragma unroll
        for (int cb = 0; cb < 4; ++cb) {
            const int col  = n0 + wc + cb * 16 + lr;
            const int part = col >> 10;
            const int hd   = col & 1023;
            const int h    = hd >> 6, d = hd & 63;
            const float bcol = bias[col];
#pragma unroll
            for (int r = 0; r < 4; ++r) {
                const int row = m0 + wr + rb * 16 + q4 * 4 + r;
                const int b   = row >> 11, k = row & 2047;
                const float val = acc[rb][cb][r] + bcol;
                if (part == 0) {
                    if (k >= 1024) {
                        const size_t o = (((size_t)(b * 16 + h)) * 1024 + (k - 1024)) * 64 + d;
                        hq_u[o] = (bf16)(val + u[hd]);
                        hq_v[o] = (bf16)(val + v[hd]);
                    }
                } else if (part == 1) {
                    hvT[(((size_t)(b * 16 + h)) * 64 + d) * 2048 + k] = (bf16)val;
                } else {
                    hk[(((size_t)(b * 16 + h)) * 2048 + k) * 64 + d] = (bf16)val;
                }
            }
        }
    }
}

// ------------------------------------------------------------------ R GEMM
__global__ __launch_bounds__(256) void k_gemm_r(
    const bf16* __restrict__ rb_, const bf16* __restrict__ Wt,
    const float* __restrict__ bias, bf16* __restrict__ hr)
{
    __shared__ bf16 lds[2 * 128 * 32];
    f32x4 acc[4][4];
    const int m0 = blockIdx.x * 128, n0 = blockIdx.y * 128;
    gemm128_core(rb_, Wt, 1024, m0, n0, lds, lds + 128 * 32, acc);

    const int lane = threadIdx.x & 63, wave = threadIdx.x >> 6;
    const int wr = (wave >> 1) * 64, wc = (wave & 1) * 64;
    const int lr = lane & 15, q4 = lane >> 4;
#pragma unroll
    for (int rb = 0; rb < 4; ++rb) {
#pragma unroll
        for (int cb = 0; cb < 4; ++cb) {
            const int col = n0 + wc + cb * 16 + lr;
            const int h = col >> 6, d = col & 63;
            const float bcol = bias[col];
#pragma unroll
            for (int r = 0; r < 4; ++r) {
                const int row = m0 + wr + rb * 16 + q4 * 4 + r;
                const int b = row >> 11, k = row & 2047;
                hr[(((size_t)(b * 16 + h)) * 2048 + k) * 64 + d] = (bf16)(acc[rb][cb][r] + bcol);
            }
        }
    }
}

// ---------------------------------------------------------------- out GEMM
__global__ __launch_bounds__(256) void k_gemm_out(
    const bf16* __restrict__ attn, const bf16* __restrict__ Wt,
    const float* __restrict__ bias, float* __restrict__ out)
{
    __shared__ bf16 lds[2 * 128 * 32];
    f32x4 acc[4][4];
    const int m0 = blockIdx.x * 128, n0 = blockIdx.y * 128;
    gemm128_core(attn, Wt, 1024, m0, n0, lds, lds + 128 * 32, acc);

    const int lane = threadIdx.x & 63, wave = threadIdx.x >> 6;
    const int wr = (wave >> 1) * 64, wc = (wave & 1) * 64;
    const int lr = lane & 15, q4 = lane >> 4;
#pragma unroll
    for (int rb = 0; rb < 4; ++rb) {
#pragma unroll
        for (int cb = 0; cb < 4; ++cb) {
            const int col = n0 + wc + cb * 16 + lr;
            const float bcol = bias[col];
#pragma unroll
            for (int r = 0; r < 4; ++r) {
                const int row = m0 + wr + rb * 16 + q4 * 4 + r;
                out[(size_t)row * 1024 + col] = acc[rb][cb][r] + bcol;
            }
        }
    }
}

// -------------------------------------- fused attention, register-pipelined
// One workgroup per (bh, 64-q tile), 64-key tiles. No online max (R8-verified).
// Software pipeline: tile t+1's global loads are issued into registers BEFORE
// computing tile t, so load latency overlaps compute; only ds_writes+barriers
// stay on the critical path. Compact U slab (R10-verified): BD view [16][84],
// Ps view [16][76]. LDS 47616 B.
__global__ __launch_bounds__(256) void k_attn(
    const bf16* __restrict__ hq_u, const bf16* __restrict__ hq_v,
    const bf16* __restrict__ hk, const bf16* __restrict__ hvT,
    const bf16* __restrict__ hr, bf16* __restrict__ attn)
{
    __shared__ bf16 Ks[64][72];        // K tile [k][d]
    __shared__ bf16 Vt[64][72];        // V tile [d][k] (pre-transposed global)
    __shared__ bf16 Rs[128][72];       // R band [j - j0][d]
    __shared__ bf16 U[4][1344];        // per-wave: BD view [16][84] / Ps view [16][76]

    const int bh = blockIdx.y;
    const int qt = blockIdx.x;
    const int q0 = qt * 64;
    const int tid = threadIdx.x, lane = tid & 63, wave = tid >> 6;
    const int lr = lane & 15, q4 = lane >> 4;
    bf16* Uw = &U[wave][0];

    const int nt = 17 + qt;                   // K-tiles for this q-tile
    const size_t kvbase = (size_t)bh * 2048 * 64;

    // fixed per-thread staging coordinates
    const int ci0  = tid,        r0_ = ci0 >> 3,  c0_ = (ci0 & 7) * 8;
    const int ci1  = 256 + tid,  r1_ = ci1 >> 3,  c1_ = (ci1 & 7) * 8;

    // prefetch register loads for tile t
    bf16x8 kv0, kv1, vv0, vv1, rv[4];
    auto load_tile = [&](int t) {
        const int k0 = t * 64;
        kv0 = *(const bf16x8*)&hk [kvbase + (size_t)(k0 + r0_) * 64 + c0_];
        kv1 = *(const bf16x8*)&hk [kvbase + (size_t)(k0 + r1_) * 64 + c1_];
        vv0 = *(const bf16x8*)&hvT[kvbase + (size_t)r0_ * 2048 + k0 + c0_];
        vv1 = *(const bf16x8*)&hvT[kvbase + (size_t)r1_ * 2048 + k0 + c1_];
        const int j0 = k0 + 1024 - q0 - 64;
#pragma unroll
        for (int p = 0; p < 4; ++p) {
            const int ci = p * 256 + tid;
            const int jrow = ci >> 3, cg = (ci & 7) * 8;
            const int j = j0 + jrow;
            bf16x8 val;
#pragma unroll
            for (int z = 0; z < 8; ++z) val[z] = (bf16)0.f;
            if (j < 2048) val = *(const bf16x8*)&hr[kvbase + (size_t)j * 64 + cg];
            rv[p] = val;
        }
    };
    auto write_tile = [&]() {
        *(bf16x8*)&Ks[r0_][c0_] = kv0;
        *(bf16x8*)&Ks[r1_][c1_] = kv1;
        *(bf16x8*)&Vt[r0_][c0_] = vv0;
        *(bf16x8*)&Vt[r1_][c1_] = vv1;
#pragma unroll
        for (int p = 0; p < 4; ++p) {
            const int ci = p * 256 + tid;
            *(bf16x8*)&Rs[ci >> 3][(ci & 7) * 8] = rv[p];
        }
    };

    // Q fragments (A-operand layout: m = lane&15, k = (lane>>4)*8 + j)
    const size_t qrow = ((size_t)bh * 1024 + q0 + wave * 16 + lr) * 64;
    const bf16x8 qu0 = *(const bf16x8*)&hq_u[qrow + q4 * 8];
    const bf16x8 qu1 = *(const bf16x8*)&hq_u[qrow + 32 + q4 * 8];
    const bf16x8 qv0 = *(const bf16x8*)&hq_v[qrow + q4 * 8];
    const bf16x8 qv1 = *(const bf16x8*)&hq_v[qrow + 32 + q4 * 8];

    f32x4 Oacc[4];
#pragma unroll
    for (int i = 0; i < 4; ++i) { Oacc[i][0] = 0.f; Oacc[i][1] = 0.f; Oacc[i][2] = 0.f; Oacc[i][3] = 0.f; }
    float lp[4] = {0.f, 0.f, 0.f, 0.f};

    // prologue: stage tile 0
    load_tile(0);
    write_tile();
    __syncthreads();

    for (int t = 0; t < nt; ++t) {
        const int k0 = t * 64;
        // issue next tile's global loads NOW (overlap with compute below)
        const int tn = (t + 1 < nt) ? t + 1 : t;
        load_tile(tn);

        // ---- AC = (hq+u) @ K^T
        f32x4 S[4];
#pragma unroll
        for (int cb = 0; cb < 4; ++cb) {
            const bf16x8 kf0 = *(const bf16x8*)&Ks[cb * 16 + lr][q4 * 8];
            const bf16x8 kf1 = *(const bf16x8*)&Ks[cb * 16 + lr][32 + q4 * 8];
            f32x4 z; z[0] = 0.f; z[1] = 0.f; z[2] = 0.f; z[3] = 0.f;
            z = __builtin_amdgcn_mfma_f32_16x16x32_bf16(qu0, kf0, z, 0, 0, 0);
            S[cb] = __builtin_amdgcn_mfma_f32_16x16x32_bf16(qu1, kf1, z, 0, 0, 0);
        }
        // ---- BD band -> compact LDS view (stride 84, col jbi*16+lr)
#pragma unroll
        for (int jbi = 0; jbi < 5; ++jbi) {
            const int jb = jbi + 3 - wave;
            const bf16x8 rf0 = *(const bf16x8*)&Rs[jb * 16 + lr][q4 * 8];
            const bf16x8 rf1 = *(const bf16x8*)&Rs[jb * 16 + lr][32 + q4 * 8];
            f32x4 z; z[0] = 0.f; z[1] = 0.f; z[2] = 0.f; z[3] = 0.f;
            z = __builtin_amdgcn_mfma_f32_16x16x32_bf16(qv0, rf0, z, 0, 0, 0);
            z = __builtin_amdgcn_mfma_f32_16x16x32_bf16(qv1, rf1, z, 0, 0, 0);
#pragma unroll
            for (int r = 0; r < 4; ++r) Uw[(q4 * 4 + r) * 84 + jbi * 16 + lr] = (bf16)z[r];
        }

        // ---- read ALL shifted BD values into registers (before Ps writes)
        float bdv[4][4];
#pragma unroll
        for (int cb = 0; cb < 4; ++cb)
#pragma unroll
            for (int r = 0; r < 4; ++r) {
                const int tq = q4 * 4 + r;
                bdv[cb][r] = (float)Uw[tq * 84 + cb * 16 + lr + 15 - tq];
            }

        // ---- scores: mask, exp (no max), accumulate l, Ps write (stride 76)
#pragma unroll
        for (int cb = 0; cb < 4; ++cb) {
            const int k = k0 + cb * 16 + lr;
#pragma unroll
            for (int r = 0; r < 4; ++r) {
                const int q = q0 + wave * 16 + q4 * 4 + r;
                const float s = (S[cb][r] + bdv[cb][r]) * 0.125f;
                const float p = (k <= 1024 + q) ? __expf(s) : 0.f;
                lp[r] += p;
                Uw[(q4 * 4 + r) * 76 + cb * 16 + lr] = (bf16)p;   // Ps view
            }
        }

        // ---- PV: P (A-layout via Ps view) @ V
        const bf16x8 pf0 = *(const bf16x8*)&Uw[lr * 76 + q4 * 8];
        const bf16x8 pf1 = *(const bf16x8*)&Uw[lr * 76 + 32 + q4 * 8];
#pragma unroll
        for (int db = 0; db < 4; ++db) {
            const bf16x8 vf0 = *(const bf16x8*)&Vt[db * 16 + lr][q4 * 8];
            const bf16x8 vf1 = *(const bf16x8*)&Vt[db * 16 + lr][32 + q4 * 8];
            Oacc[db] = __builtin_amdgcn_mfma_f32_16x16x32_bf16(pf0, vf0, Oacc[db], 0, 0, 0);
            Oacc[db] = __builtin_amdgcn_mfma_f32_16x16x32_bf16(pf1, vf1, Oacc[db], 0, 0, 0);
        }
        __syncthreads();           // everyone done reading tile t
        write_tile();              // stage tile t+1 from prefetched regs
        __syncthreads();           // tile t+1 visible
    }

    // ---- 16-lane row-sum of l, normalize, write
#pragma unroll
    for (int off = 1; off < 16; off <<= 1)
#pragma unroll
        for (int r = 0; r < 4; ++r) lp[r] += __shfl_xor(lp[r], off, 64);

    const int b = bh >> 4, h = bh & 15;
#pragma unroll
    for (int r = 0; r < 4; ++r) {
        const float rl = 1.f / lp[r];
        const int q = q0 + wave * 16 + q4 * 4 + r;
#pragma unroll
        for (int db = 0; db < 4; ++db) {
            const int d = db * 16 + lr;
            attn[(((size_t)b * 1024 + q) * 16 + h) * 64 + d] = (bf16)(Oacc[db][r] * rl);
        }
    }
}

// ------------------------------------------------------------------ launch
extern "C" void kernel_launch(void* const* d_in, const int* in_sizes, int n_in,
                              void* d_out, int out_size, void* d_ws, size_t ws_size,
                              hipStream_t stream)
{
    const float* inputs = (const float*)d_in[0];
    const float* mem    = (const float*)d_in[1];
    const float* r      = (const float*)d_in[2];
    const float* W_qkv  = (const float*)d_in[3];
    const float* b_qkv  = (const float*)d_in[4];
    const float* W_r    = (const float*)d_in[5];
    const float* b_r    = (const float*)d_in[6];
    const float* W_o    = (const float*)d_in[7];
    const float* b_o    = (const float*)d_in[8];
    const float* u      = (const float*)d_in[9];
    const float* v      = (const float*)d_in[10];
    float* out = (float*)d_out;

    char* ws = (char*)d_ws;
    size_t off = 0;
    auto alloc = [&](size_t bytes) -> void* {
        void* p = ws + off;
        off += (bytes + 255) & ~(size_t)255;
        return p;
    };
    bf16* hq_u  = (bf16*)alloc(2ull * 16 * 1024 * 64 * 2);
    bf16* hq_v  = (bf16*)alloc(2ull * 16 * 1024 * 64 * 2);
    bf16* hk    = (bf16*)alloc(2ull * 16 * 2048 * 64 * 2);
    bf16* hvT   = (bf16*)alloc(2ull * 16 * 2048 * 64 * 2);
    bf16* hr    = (bf16*)alloc(2ull * 16 * 2048 * 64 * 2);
    bf16* attnb = (bf16*)alloc(2ull * 1024 * 1024 * 2);
    bf16* Wot   = (bf16*)alloc(1024ull * 1024 * 2);
    bf16* catb  = (bf16*)alloc(4096ull * 1024 * 2);
    bf16* rb    = (bf16*)alloc(4096ull * 1024 * 2);
    bf16* Wqkvt = (bf16*)alloc(3072ull * 1024 * 2);
    bf16* Wrt   = (bf16*)alloc(1024ull * 1024 * 2);

    k_tcast<<<dim3(96, 32), 256, 0, stream>>>(W_qkv, Wqkvt, 1024, 3072);
    k_tcast<<<dim3(32, 32), 256, 0, stream>>>(W_r, Wrt, 1024, 1024);
    k_tcast<<<dim3(32, 32), 256, 0, stream>>>(W_o, Wot, 1024, 1024);
    k_cast_cat<<<4096, 256, 0, stream>>>(mem, inputs, catb);
    k_cast<<<4096, 256, 0, stream>>>(r, rb);

    k_gemm_qkv<<<dim3(32, 24), 256, 0, stream>>>(catb, Wqkvt, b_qkv, u, v, hq_u, hq_v, hk, hvT);
    k_gemm_r<<<dim3(32, 8), 256, 0, stream>>>(rb, Wrt, b_r, hr);
    k_attn<<<dim3(16, 32), 256, 0, stream>>>(hq_u, hq_v, hk, hvT, hr, attnb);
    k_gemm_out<<<dim3(16, 8), 256, 0, stream>>>(attnb, Wot, b_o, out);
}